// Round 11
// baseline (175.604 us; speedup 1.0000x reference)
//
#include <hip/hip_runtime.h>
#include <hip/hip_bf16.h>
#include <math.h>

// Problem constants
constexpr int Bc = 2, Lc = 1024, Dc = 768, Hc = 12, dh = 64, Rc = 128;
constexpr int BL = Bc * Lc;          // 2048 tokens
constexpr int TD = 3 * Dc;           // 2304
constexpr int CH = 64;               // chunk length
constexpr int NC = Lc / CH;          // 16 chunks per sequence
constexpr int BH = Bc * Hc;          // 24
constexpr int NMEGA = BH * NC;       // 384 blocks

typedef __attribute__((ext_vector_type(8))) short bf16x8;
typedef __attribute__((ext_vector_type(4))) float f32x4;

__device__ __forceinline__ float bf2f(short u) {
    union { float f; unsigned int i; } c;
    c.i = ((unsigned int)(unsigned short)u) << 16;
    return c.f;
}
__device__ __forceinline__ short f2b(float f) {
    __hip_bfloat16 h = __float2bfloat16(f);
    return *reinterpret_cast<short*>(&h);
}

#define GLOAD_LDS16(gp, lp)                                                        \
    __builtin_amdgcn_global_load_lds(                                              \
        (const __attribute__((address_space(1))) void*)(gp),                       \
        (__attribute__((address_space(3))) void*)(lp), 16, 0, 0)

// Manual grid barrier (each idx used exactly once per launch).
// Counters must be zeroed before kernel start (hipMemsetAsync in kernel_launch).
__device__ __forceinline__ void grid_barrier(unsigned* bar, int idx, unsigned nb) {
    __syncthreads();                               // all block's mem ops drained
    if (threadIdx.x == 0) {
        unsigned* cnt   = bar + idx * 16;
        unsigned* sense = bar + idx * 16 + 8;
        __threadfence();                           // release: writeback L2
        unsigned old = atomicAdd(sense, 0u);       // sample generation (pre-arrive)
        if (atomicAdd(cnt, 1u) == nb - 1) {
            atomicExch(cnt, 0u);                   // self-restore for replay
            __threadfence();
            atomicAdd(sense, 1u);
        } else {
            while (atomicAdd(sense, 0u) == old)
                __builtin_amdgcn_s_sleep(8);
        }
        __threadfence();                           // acquire: invalidate stale
    }
    __syncthreads();
}

// ---------------- Prep: 3 weight transposes + LayerNorm, one kernel ----------------
__device__ __forceinline__ void do_transpose(const float* __restrict__ W,
                                             __hip_bfloat16* __restrict__ WT,
                                             int K, int N, int bx, int by,
                                             int tid, float* t) {
    int k0 = by * 32, n0 = bx * 32;
    int r = tid >> 5, c = tid & 31;   // r in 0..7
#pragma unroll
    for (int i = 0; i < 4; i++)
        t[(r + i * 8) * 33 + c] = W[(size_t)(k0 + r + i * 8) * N + n0 + c];
    __syncthreads();
#pragma unroll
    for (int i = 0; i < 4; i++)
        WT[(size_t)(n0 + r + i * 8) * K + k0 + c] = __float2bfloat16(t[c * 33 + r + i * 8]);
}

constexpr int NT1 = (TD / 32) * (Dc / 32);   // 1728  Wqkv
constexpr int NT2 = (Dc / 32) * (Dc / 32);   // 576   Wproj
constexpr int NT3 = (Rc / 32) * (Dc / 32);   // 96    Wb1
constexpr int NPREP = NT1 + NT2 + NT3 + BL;  // + 2048 LN rows

__global__ __launch_bounds__(256)
void prep_kernel(const float* __restrict__ x, const float* __restrict__ ln_w,
                 const float* __restrict__ ln_b,
                 const float* __restrict__ Wqkv, const float* __restrict__ Wproj,
                 const float* __restrict__ Wb1,
                 __hip_bfloat16* __restrict__ xnb, __hip_bfloat16* __restrict__ xb,
                 __hip_bfloat16* __restrict__ WqkvT, __hip_bfloat16* __restrict__ WprojT,
                 __hip_bfloat16* __restrict__ Wb1T) {
    __shared__ float shm[32 * 33];
    int bid = blockIdx.x, tid = threadIdx.x;
    if (bid < NT1) { do_transpose(Wqkv, WqkvT, Dc, TD, bid % 72, bid / 72, tid, shm); return; }
    bid -= NT1;
    if (bid < NT2) { do_transpose(Wproj, WprojT, Dc, Dc, bid % 24, bid / 24, tid, shm); return; }
    bid -= NT2;
    if (bid < NT3) { do_transpose(Wb1, Wb1T, Dc, Rc, bid % 4, bid / 4, tid, shm); return; }
    bid -= NT3;
    // LayerNorm row
    int row = bid;
    const float* xr = x + (size_t)row * Dc;
    __hip_bfloat16* yr = xnb + (size_t)row * Dc;
    __hip_bfloat16* xbr = xb + (size_t)row * Dc;
    float v[3];
    float s = 0.f;
#pragma unroll
    for (int i = 0; i < 3; i++) { v[i] = xr[tid + i * 256]; s += v[i]; }
    shm[tid] = s; __syncthreads();
    for (int off = 128; off > 0; off >>= 1) {
        if (tid < off) shm[tid] += shm[tid + off];
        __syncthreads();
    }
    float mu = shm[0] / (float)Dc;
    __syncthreads();
    float s2 = 0.f;
#pragma unroll
    for (int i = 0; i < 3; i++) { float d = v[i] - mu; s2 += d * d; }
    shm[tid] = s2; __syncthreads();
    for (int off = 128; off > 0; off >>= 1) {
        if (tid < off) shm[tid] += shm[tid + off];
        __syncthreads();
    }
    float rstd = rsqrtf(shm[0] / (float)Dc + 1e-5f);
#pragma unroll
    for (int i = 0; i < 3; i++) {
        int c = tid + i * 256;
        yr[c] = __float2bfloat16((v[i] - mu) * rstd * ln_w[c] + ln_b[c]);
        xbr[c] = __float2bfloat16(v[i]);
    }
}

// ---------------- Fat GEMM: 128x64 tiles, 4 waves, 608 blocks (qkv 576 + bneck 32) ----------------
constexpr int NQB = (BL / 128) * (TD / 64);    // 576
constexpr int NFAT = NQB + (BL / 128) * 2;     // 608
__global__ __launch_bounds__(256)
void fat_gemm_kernel(const __hip_bfloat16* __restrict__ A1,
                     const __hip_bfloat16* __restrict__ B1,
                     const float* __restrict__ bias1,
                     __hip_bfloat16* __restrict__ C1,
                     const __hip_bfloat16* __restrict__ A2,
                     const __hip_bfloat16* __restrict__ B2,
                     float* __restrict__ C2) {
    __shared__ short lds[2][128 * 64 + 64 * 64];   // A tile then B tile, 24 KB/buf
    int bid = blockIdx.x;
    bid = (bid & 7) * (NFAT / 8) + (bid >> 3);     // bijective: 608 % 8 == 0
    bool isq = bid < NQB;
    int bx, by, N;
    const __hip_bfloat16 *A, *BT;
    if (isq) { bx = bid % 36; by = bid / 36; A = A1; BT = B1; N = TD; }
    else     { int b2 = bid - NQB; bx = b2 % 2; by = b2 / 2; A = A2; BT = B2; N = Rc; }
    const int K = Dc;

    int tid = threadIdx.x;
    int wave = tid >> 6, lane = tid & 63;
    int l16 = lane & 15, l4 = lane >> 4;
    int m0 = by * 128, n0 = bx * 64;

    int r_in = lane >> 3;                     // 0..7
    int s_src = (lane & 7) ^ r_in;            // inverse-swizzled source slot
    const __hip_bfloat16* gsrcA = A  + (size_t)(m0 + wave * 32 + r_in) * K + s_src * 8;
    const __hip_bfloat16* gsrcB = BT + (size_t)(n0 + wave * 16 + r_in) * K + s_src * 8;

    int wr = (wave >> 1) * 64, wc = (wave & 1) * 32;
    int xs = l16 & 7;                         // read-side XOR (== row & 7)

    f32x4 acc[4][2];
#pragma unroll
    for (int i = 0; i < 4; i++)
#pragma unroll
        for (int j = 0; j < 2; j++) acc[i][j] = f32x4{0.f, 0.f, 0.f, 0.f};

    auto stage = [&](int buf, int kt) {
        short* lbA = &lds[buf][(wave * 32) * 64];
        short* lbB = &lds[buf][128 * 64 + (wave * 16) * 64];
        const __hip_bfloat16* gA = gsrcA + kt * 64;
        const __hip_bfloat16* gB = gsrcB + kt * 64;
#pragma unroll
        for (int i = 0; i < 4; i++)           // A: 32 rows/wave
            GLOAD_LDS16(gA + (size_t)i * 8 * K, lbA + i * 8 * 64);
#pragma unroll
        for (int i = 0; i < 2; i++)           // B: 16 rows/wave
            GLOAD_LDS16(gB + (size_t)i * 8 * K, lbB + i * 8 * 64);
    };
    auto compute = [&](int buf) {
        const short* As = &lds[buf][0];
        const short* Bs = &lds[buf][128 * 64];
#pragma unroll
        for (int kk = 0; kk < 2; kk++) {
            bf16x8 af[4], bfr[2];
            int slot = (kk * 4 + l4) ^ xs;
#pragma unroll
            for (int f = 0; f < 4; f++)
                af[f] = *reinterpret_cast<const bf16x8*>(
                    &As[(wr + f * 16 + l16) * 64 + slot * 8]);
#pragma unroll
            for (int f = 0; f < 2; f++)
                bfr[f] = *reinterpret_cast<const bf16x8*>(
                    &Bs[(wc + f * 16 + l16) * 64 + slot * 8]);
#pragma unroll
            for (int i = 0; i < 4; i++)
#pragma unroll
                for (int j = 0; j < 2; j++)
                    acc[i][j] = __builtin_amdgcn_mfma_f32_16x16x32_bf16(
                        af[i], bfr[j], acc[i][j], 0, 0, 0);
        }
    };

    int NT = K / 64;
    int cur = 0;
    stage(0, 0);
    __syncthreads();
    for (int t = 0; t < NT; t++) {
        if (t + 1 < NT) stage(cur ^ 1, t + 1);
        compute(cur);
        if (t + 1 < NT) { __syncthreads(); cur ^= 1; }
    }

    int crow = l4 * 4;
#pragma unroll
    for (int i = 0; i < 4; i++) {
#pragma unroll
        for (int j = 0; j < 2; j++) {
            int col = n0 + wc + j * 16 + l16;
            float bb = isq ? bias1[col] : 0.f;
#pragma unroll
            for (int r = 0; r < 4; r++) {
                int rowm = m0 + wr + i * 16 + crow + r;
                float v = acc[i][j][r] + bb;
                if (isq) {
                    C1[(size_t)rowm * N + col] = __float2bfloat16(v);
                } else {
                    v = v / (1.f + expf(-v));            // silu
                    C2[(size_t)rowm * N + col] = v;
                }
            }
        }
    }
}

// ---------------- Mega kernel: phaseA + prefix + phaseC + proj, manual grid barriers ----------------
// grid = 384 blocks x 256 thr. LDS 50.7 KB -> <=3 blocks/CU; launch_bounds(256,2)
// guarantees >=2 blocks/CU by VGPR -> capacity 512 >= 384 (all co-resident).
constexpr int LQ = 72;    // padded row stride (shorts)
__global__ __launch_bounds__(256, 2)
void mega_kernel(const __hip_bfloat16* __restrict__ qkv, const float* __restrict__ tbuf,
                 const float* __restrict__ Wb2, const float* __restrict__ temperature,
                 float* __restrict__ gate_out, float* __restrict__ SU, float* __restrict__ zc,
                 const float* __restrict__ mn_w, const float* __restrict__ mn_b,
                 __hip_bfloat16* __restrict__ attn,
                 const __hip_bfloat16* __restrict__ WprojT, const float* __restrict__ bproj,
                 float* __restrict__ out0, unsigned* __restrict__ bar) {
    alignas(16) __shared__ char pool[50688];
    short* VT   = (short*)pool;                   // [80][LQ] V^T*og; row64=ones; 65-79=0 (persists A->C)
    short* KsT  = (short*)(pool + 11520);         // phaseA [64][LQ] K^T; aliased as Ps in phaseC
    short* Qs   = (short*)(pool + 20736);         // [64][LQ] elu(Q) row-major (persists)
    short* KsRM = (short*)(pool + 29952);         // [64][LQ] elu(K) row-major (persists)
    float* w2s  = (float*)(pool + 39168);         // [5][128] (phaseA only)
    float* ogs  = (float*)(pool + 41728);         // [64]     (phaseA only)
    short* BstS = (short*)(pool + 39168);         // [80][LQ] S^T + z row (phaseC, aliases w2s/ogs)

    int bid = blockIdx.x;
    int tid = threadIdx.x;
    int wave = tid >> 6, lane = tid & 63;
    int l16 = lane & 15, l4 = lane >> 4;

    int bh = bid >> 4, c = bid & 15;
    int b = bh / Hc, h = bh % Hc;
    int tok0 = b * Lc + c * CH;

    // ================= phase A =================
    for (int i = tid; i < 640; i += 256) {
        int cc = i >> 7, r = i & 127;
        w2s[i] = Wb2[r * (Hc * 5) + h * 5 + cc];
    }
    bf16x8 q8[2], k8[2], v8[2];
#pragma unroll
    for (int i = 0; i < 2; i++) {
        int c8 = tid + i * 256;
        int tt = c8 >> 3, d8 = (c8 & 7) * 8;
        size_t rowoff = (size_t)(tok0 + tt) * TD + h * dh;
        q8[i] = *reinterpret_cast<const bf16x8*>(qkv + rowoff + d8);
        k8[i] = *reinterpret_cast<const bf16x8*>(qkv + rowoff + Dc + d8);
        v8[i] = *reinterpret_cast<const bf16x8*>(qkv + rowoff + 2 * Dc + d8);
    }
    for (int i = tid; i < 15 * LQ; i += 256) VT[65 * LQ + i] = 0;
    if (tid < 64) VT[64 * LQ + tid] = f2b(1.0f);
    __syncthreads();   // w2s ready

    {   // gate: 4 lanes per token
        int tt = tid >> 2, sub = tid & 3;
        const float* tr = tbuf + (size_t)(tok0 + tt) * Rc + sub * 32;
        float p[5] = {};
        for (int r4 = 0; r4 < 32; r4 += 4) {
            float4 tv = *reinterpret_cast<const float4*>(tr + r4);
#pragma unroll
            for (int cc = 0; cc < 5; cc++) {
                float4 w4 = *reinterpret_cast<const float4*>(&w2s[cc * 128 + sub * 32 + r4]);
                p[cc] = fmaf(tv.x, w4.x, fmaf(tv.y, w4.y,
                        fmaf(tv.z, w4.z, fmaf(tv.w, w4.w, p[cc]))));
            }
        }
#pragma unroll
        for (int cc = 0; cc < 5; cc++) {
            p[cc] += __shfl_xor(p[cc], 1, 64);
            p[cc] += __shfl_xor(p[cc], 2, 64);
        }
        if (sub == 0) {
            const float PI = 3.14159265358979323846f;
            float sem_amp = 1.f / (1.f + expf(-p[0]));
            float sem_phase = tanhf(p[1]) * PI;
            float ctx_amp = 1.f / (1.f + expf(-p[2]));
            float ctx_phase = tanhf(p[3]) * PI;
            float temp = fminf(fmaxf(temperature[0], 0.1f), 2.0f);
            float inter = tanhf(sem_amp * ctx_amp * cosf(sem_phase - ctx_phase)) * temp;
            float g = 1.f / (1.f + expf(-inter));
            gate_out[(size_t)(tok0 + tt) * Hc + h] = g;
            ogs[tt] = 1.f + g;
        }
    }
    __syncthreads();   // ogs ready

    // staging: KsT[d][t], VT[e][t], Qs[l][d], KsRM[t][d]
#pragma unroll
    for (int i = 0; i < 2; i++) {
        int c8 = tid + i * 256;
        int tt = c8 >> 3, d8 = (c8 & 7) * 8;
        float gv = ogs[tt];
        short qo[8], ko[8];
#pragma unroll
        for (int j = 0; j < 8; j++) {
            float qv = bf2f(q8[i][j]);
            qo[j] = f2b(qv > 0.f ? qv + 1.f : expf(qv));
            float kv = bf2f(k8[i][j]);
            ko[j] = f2b(kv > 0.f ? kv + 1.f : expf(kv));
            KsT[(d8 + j) * LQ + tt] = ko[j];
            VT[(d8 + j) * LQ + tt]  = f2b(bf2f(v8[i][j]) * gv);
        }
        *reinterpret_cast<bf16x8*>(&Qs[tt * LQ + d8])   = *reinterpret_cast<bf16x8*>(qo);
        *reinterpret_cast<bf16x8*>(&KsRM[tt * LQ + d8]) = *reinterpret_cast<bf16x8*>(ko);
    }
    __syncthreads();

    {   // U[d][e] = sum_t K[t][d]*Vog[t][e]; col e=64 -> zc[d]
        const short* arow = &KsT[(wave * 16 + l16) * LQ];
        f32x4 acc[5];
#pragma unroll
        for (int j = 0; j < 5; j++) acc[j] = f32x4{0.f, 0.f, 0.f, 0.f};
#pragma unroll
        for (int kk = 0; kk < 2; kk++) {
            bf16x8 af = *reinterpret_cast<const bf16x8*>(&arow[kk * 32 + l4 * 8]);
#pragma unroll
            for (int j = 0; j < 5; j++) {
                bf16x8 bfv = *reinterpret_cast<const bf16x8*>(
                    &VT[(j * 16 + l16) * LQ + kk * 32 + l4 * 8]);
                acc[j] = __builtin_amdgcn_mfma_f32_16x16x32_bf16(af, bfv, acc[j], 0, 0, 0);
            }
        }
        int dbase = wave * 16 + l4 * 4;
        float* SUo = SU + (size_t)bid * 4096;
#pragma unroll
        for (int j = 0; j < 4; j++) {
            int e = j * 16 + l16;
#pragma unroll
            for (int r = 0; r < 4; r++)
                SUo[e * 64 + dbase + r] = acc[j][r];
        }
        if (l16 == 0) {
#pragma unroll
            for (int r = 0; r < 4; r++)
                zc[bid * 64 + dbase + r] = acc[4][r];
        }
    }
    grid_barrier(bar, 0, NMEGA);

    // ================= prefix (grid covers BH*4096 exactly) =================
    {
        int gid = bid * 256 + tid;
        int pbh = gid >> 12, i = gid & 4095;
        float* S = SU + (size_t)pbh * NC * 4096 + i;
        float r[NC];
#pragma unroll
        for (int cc = 0; cc < NC; cc++) r[cc] = S[cc * 4096];
        float run = 0.f;
#pragma unroll
        for (int cc = 0; cc < NC; cc++) { float tv = r[cc]; S[cc * 4096] = run; run += tv; }
        if (gid < BH * 64) {
            int zbh = gid >> 6, zi = gid & 63;
            float* z = zc + (size_t)zbh * NC * 64 + zi;
            float rz[NC];
#pragma unroll
            for (int cc = 0; cc < NC; cc++) rz[cc] = z[cc * 64];
            float runz = 0.f;
#pragma unroll
            for (int cc = 0; cc < NC; cc++) { float tv = rz[cc]; z[cc * 64] = runz; runz += tv; }
        }
    }
    grid_barrier(bar, 1, NMEGA);

    // ================= phase C =================
    {
        const float* SUp = SU + (size_t)bid * 4096;
        const float* zcp = zc + (size_t)bid * 64;
#pragma unroll
        for (int i = 0; i < 2; i++) {
            int c8 = tid + i * 256;
            int tt = c8 >> 3, d8 = (c8 & 7) * 8;
            float4 sa = *reinterpret_cast<const float4*>(SUp + tt * 64 + d8);
            float4 sb = *reinterpret_cast<const float4*>(SUp + tt * 64 + d8 + 4);
            short so[8] = { f2b(sa.x), f2b(sa.y), f2b(sa.z), f2b(sa.w),
                            f2b(sb.x), f2b(sb.y), f2b(sb.z), f2b(sb.w) };
            *reinterpret_cast<bf16x8*>(&BstS[tt * LQ + d8]) = *reinterpret_cast<bf16x8*>(so);
        }
        if (tid < 64) BstS[64 * LQ + tid] = f2b(zcp[tid]);
        for (int i = tid; i < 15 * LQ; i += 256) BstS[65 * LQ + i] = 0;

        // P = Qf Kf^T (Qs x KsRM), mask, spill to Ps (= KsT alias; KsT dead)
        const short* qrow = &Qs[(wave * 16 + l16) * LQ];
        short* Ps = KsT;
        f32x4 accp[4];
#pragma unroll
        for (int j = 0; j < 4; j++) accp[j] = f32x4{0.f, 0.f, 0.f, 0.f};
#pragma unroll
        for (int kk = 0; kk < 2; kk++) {
            bf16x8 af = *reinterpret_cast<const bf16x8*>(&qrow[kk * 32 + l4 * 8]);
#pragma unroll
            for (int j = 0; j < 4; j++) {
                bf16x8 bfv = *reinterpret_cast<const bf16x8*>(
                    &KsRM[(j * 16 + l16) * LQ + kk * 32 + l4 * 8]);
                accp[j] = __builtin_amdgcn_mfma_f32_16x16x32_bf16(af, bfv, accp[j], 0, 0, 0);
            }
        }
#pragma unroll
        for (int j = 0; j < 4; j++) {
#pragma unroll
            for (int r = 0; r < 4; r++) {
                int l = wave * 16 + l4 * 4 + r;
                int t = j * 16 + l16;
                float pv = (t <= l) ? accp[j][r] : 0.f;
                Ps[l * LQ + t] = f2b(pv);
            }
        }
        __syncthreads();   // Ps + BstS ready

        // O = P @ VT^T (kk 0-1) + Qf @ BstS^T (kk 2-3); j=4 col e=64 = den
        const short* prow = &Ps[(wave * 16 + l16) * LQ];
        f32x4 acc[5];
#pragma unroll
        for (int j = 0; j < 5; j++) acc[j] = f32x4{0.f, 0.f, 0.f, 0.f};
#pragma unroll
        for (int kk = 0; kk < 4; kk++) {
            bf16x8 af = (kk < 2)
                ? *reinterpret_cast<const bf16x8*>(&prow[kk * 32 + l4 * 8])
                : *reinterpret_cast<const bf16x8*>(&qrow[(kk - 2) * 32 + l4 * 8]);
#pragma unroll
            for (int j = 0; j < 5; j++) {
                const short* btile = (kk < 2)
                    ? &VT[(j * 16 + l16) * LQ + kk * 32 + l4 * 8]
                    : &BstS[(j * 16 + l16) * LQ + (kk - 2) * 32 + l4 * 8];
                bf16x8 bfv = *reinterpret_cast<const bf16x8*>(btile);
                acc[j] = __builtin_amdgcn_mfma_f32_16x16x32_bf16(af, bfv, acc[j], 0, 0, 0);
            }
        }
        // epilogue: den, mini-LN over e, bf16 store
#pragma unroll
        for (int r = 0; r < 4; r++) {
            float den = __shfl(acc[4][r], l4 * 16) + 1e-6f;
            float inv = 1.f / den;
            float v0 = acc[0][r] * inv, v1 = acc[1][r] * inv;
            float v2 = acc[2][r] * inv, v3 = acc[3][r] * inv;
            float s1 = v0 + v1 + v2 + v3;
            float s2 = v0 * v0 + v1 * v1 + v2 * v2 + v3 * v3;
#pragma unroll
            for (int m = 1; m < 16; m <<= 1) {
                s1 += __shfl_xor(s1, m, 64);
                s2 += __shfl_xor(s2, m, 64);
            }
            float mu = s1 * (1.f / 64.f);
            float rstd = rsqrtf(s2 * (1.f / 64.f) - mu * mu + 1e-5f);
            int l = wave * 16 + l4 * 4 + r;
            __hip_bfloat16* orow = attn + (size_t)(tok0 + l) * Dc + h * dh;
            float vj[4] = {v0, v1, v2, v3};
#pragma unroll
            for (int j = 0; j < 4; j++) {
                int e = j * 16 + l16;
                orow[e] = __float2bfloat16((vj[j] - mu) * rstd * mn_w[e] + mn_b[e]);
            }
        }
    }
    grid_barrier(bar, 2, NMEGA);

    // ================= proj: out0 = attn @ WprojT^T + bproj (64x64 tiles) =================
    {
        short* plds = (short*)pool;            // [2][8192] shorts, aliases dead A/C data
        const int K = Dc, N = Dc, nbx = Dc / 64;
        int pbid = (bid & 7) * 48 + (bid >> 3);            // 384 % 8 == 0 bijective
        int m0 = (pbid / nbx) * 64, n0 = (pbid % nbx) * 64;

        int r_in = lane >> 3;
        int s_src = (lane & 7) ^ r_in;
        const __hip_bfloat16* gsrc = (wave < 2)
            ? attn   + (size_t)(m0 + wave * 32 + r_in) * K + s_src * 8
            : WprojT + (size_t)(n0 + (wave - 2) * 32 + r_in) * K + s_src * 8;

        int wr = (wave >> 1) * 32, wc = (wave & 1) * 32;
        int xs = l16 & 7;

        f32x4 acc[2][2];
#pragma unroll
        for (int i = 0; i < 2; i++)
#pragma unroll
            for (int j = 0; j < 2; j++) acc[i][j] = f32x4{0.f, 0.f, 0.f, 0.f};

        auto stage = [&](int buf, int kt) {
            const __hip_bfloat16* g = gsrc + kt * 64;
            short* lb = plds + buf * 8192 + wave * 32 * 64;
#pragma unroll
            for (int i = 0; i < 4; i++)
                GLOAD_LDS16(g + (size_t)i * 8 * K, lb + i * 8 * 64);
        };
        auto compute = [&](int buf) {
            const short* As = plds + buf * 8192;
            const short* Bs = plds + buf * 8192 + 64 * 64;
#pragma unroll
            for (int kk = 0; kk < 2; kk++) {
                bf16x8 af[2], bfr[2];
                int slot = (kk * 4 + l4) ^ xs;
#pragma unroll
                for (int f = 0; f < 2; f++) {
                    af[f]  = *reinterpret_cast<const bf16x8*>(
                        &As[(wr + f * 16 + l16) * 64 + slot * 8]);
                    bfr[f] = *reinterpret_cast<const bf16x8*>(
                        &Bs[(wc + f * 16 + l16) * 64 + slot * 8]);
                }
#pragma unroll
                for (int i = 0; i < 2; i++)
#pragma unroll
                    for (int j = 0; j < 2; j++)
                        acc[i][j] = __builtin_amdgcn_mfma_f32_16x16x32_bf16(
                            af[i], bfr[j], acc[i][j], 0, 0, 0);
            }
        };

        int NT = K / 64;
        int cur = 0;
        stage(0, 0);
        __syncthreads();
        for (int t = 0; t < NT; t++) {
            if (t + 1 < NT) stage(cur ^ 1, t + 1);
            compute(cur);
            if (t + 1 < NT) { __syncthreads(); cur ^= 1; }
        }

        int crow = l4 * 4;
#pragma unroll
        for (int i = 0; i < 2; i++) {
#pragma unroll
            for (int j = 0; j < 2; j++) {
                int col = n0 + wc + j * 16 + l16;
                float bb = bproj[col];
#pragma unroll
                for (int r = 0; r < 4; r++) {
                    int rowm = m0 + wr + i * 16 + crow + r;
                    out0[(size_t)rowm * N + col] = acc[i][j][r] + bb;
                }
            }
        }
    }
}

extern "C" void kernel_launch(void* const* d_in, const int* in_sizes, int n_in,
                              void* d_out, int out_size, void* d_ws, size_t ws_size,
                              hipStream_t stream) {
    const float* x     = (const float*)d_in[0];
    const float* Wqkv  = (const float*)d_in[1];
    const float* bqkv  = (const float*)d_in[2];
    const float* Wb1   = (const float*)d_in[3];
    const float* Wb2   = (const float*)d_in[4];
    const float* temp  = (const float*)d_in[5];
    const float* Wproj = (const float*)d_in[6];
    const float* bproj = (const float*)d_in[7];
    const float* ln_w  = (const float*)d_in[8];
    const float* ln_b  = (const float*)d_in[9];
    const float* mn_w  = (const float*)d_in[10];
    const float* mn_b  = (const float*)d_in[11];

    float* out0 = (float*)d_out;                 // [2048, 768]
    float* gate = out0 + (size_t)BL * Dc;        // [2048, 12]

    unsigned* bar = (unsigned*)d_ws;             // 64 u32 barrier space
    float* tbuf = (float*)d_ws + 64;             // 2048*128 f32
    float* SU   = tbuf + (size_t)BL * Rc;        // 24*16*4096 f32 (U^T, [e][d])
    float* zc   = SU + (size_t)BH * NC * 4096;   // 24*16*64 f32
    __hip_bfloat16* bfr = (__hip_bfloat16*)(zc + (size_t)BH * NC * 64);
    __hip_bfloat16* qkvb   = bfr;                        // 2048*2304 bf16
    __hip_bfloat16* xnb    = qkvb + (size_t)BL * TD;     // 2048*768 bf16
    __hip_bfloat16* xb     = xnb + (size_t)BL * Dc;      // 2048*768 bf16 (raw x)
    __hip_bfloat16* attnb  = xb + (size_t)BL * Dc;       // 2048*768 bf16
    __hip_bfloat16* WqkvT  = attnb + (size_t)BL * Dc;    // 2304*768 bf16
    __hip_bfloat16* WprojT = WqkvT + (size_t)TD * Dc;    // 768*768 bf16
    __hip_bfloat16* Wb1T   = WprojT + (size_t)Dc * Dc;   // 128*768 bf16

    // 0. zero the grid-barrier counters (graph-capturable memset node)
    hipMemsetAsync(bar, 0, 256, stream);
    // 1. prep: weight transposes + LayerNorm
    prep_kernel<<<NPREP, 256, 0, stream>>>(x, ln_w, ln_b, Wqkv, Wproj, Wb1,
                                           xnb, xb, WqkvT, WprojT, Wb1T);
    // 2. fat dispatch: qkv GEMM (bf16 out) + bottleneck silu GEMM (fp32 out)
    fat_gemm_kernel<<<NFAT, 256, 0, stream>>>(xnb, WqkvT, bqkv, qkvb, xb, Wb1T, tbuf);
    // 3. mega: phaseA + prefix + phaseC + proj with manual grid barriers
    mega_kernel<<<NMEGA, 256, 0, stream>>>(qkvb, tbuf, Wb2, temp, gate, SU, zc,
                                           mn_w, mn_b, attnb, WprojT, bproj, out0, bar);
}

// Round 12
// 103.084 us; speedup vs baseline: 1.7035x; 1.7035x over previous
//
#include <hip/hip_runtime.h>
#include <hip/hip_bf16.h>
#include <math.h>

// Problem constants
constexpr int Bc = 2, Lc = 1024, Dc = 768, Hc = 12, dh = 64, Rc = 128;
constexpr int BL = Bc * Lc;          // 2048 tokens
constexpr int TD = 3 * Dc;           // 2304
constexpr int CH = 64;               // chunk length
constexpr int NC = Lc / CH;          // 16 chunks per sequence
constexpr int BH = Bc * Hc;          // 24

typedef __attribute__((ext_vector_type(8))) short bf16x8;
typedef __attribute__((ext_vector_type(4))) float f32x4;

__device__ __forceinline__ float bf2f(short u) {
    union { float f; unsigned int i; } c;
    c.i = ((unsigned int)(unsigned short)u) << 16;
    return c.f;
}
__device__ __forceinline__ short f2b(float f) {
    __hip_bfloat16 h = __float2bfloat16(f);
    return *reinterpret_cast<short*>(&h);
}

#define GLOAD_LDS16(gp, lp)                                                        \
    __builtin_amdgcn_global_load_lds(                                              \
        (const __attribute__((address_space(1))) void*)(gp),                       \
        (__attribute__((address_space(3))) void*)(lp), 16, 0, 0)

// ---------------- Prep: 3 weight transposes + LayerNorm, one kernel ----------------
__device__ __forceinline__ void do_transpose(const float* __restrict__ W,
                                             __hip_bfloat16* __restrict__ WT,
                                             int K, int N, int bx, int by,
                                             int tid, float* t) {
    int k0 = by * 32, n0 = bx * 32;
    int r = tid >> 5, c = tid & 31;   // r in 0..7
#pragma unroll
    for (int i = 0; i < 4; i++)
        t[(r + i * 8) * 33 + c] = W[(size_t)(k0 + r + i * 8) * N + n0 + c];
    __syncthreads();
#pragma unroll
    for (int i = 0; i < 4; i++)
        WT[(size_t)(n0 + r + i * 8) * K + k0 + c] = __float2bfloat16(t[c * 33 + r + i * 8]);
}

constexpr int NT1 = (TD / 32) * (Dc / 32);   // 1728  Wqkv
constexpr int NT2 = (Dc / 32) * (Dc / 32);   // 576   Wproj
constexpr int NT3 = (Rc / 32) * (Dc / 32);   // 96    Wb1
constexpr int NPREP = NT1 + NT2 + NT3 + BL;  // + 2048 LN rows

__global__ __launch_bounds__(256)
void prep_kernel(const float* __restrict__ x, const float* __restrict__ ln_w,
                 const float* __restrict__ ln_b,
                 const float* __restrict__ Wqkv, const float* __restrict__ Wproj,
                 const float* __restrict__ Wb1,
                 __hip_bfloat16* __restrict__ xnb, __hip_bfloat16* __restrict__ xb,
                 __hip_bfloat16* __restrict__ WqkvT, __hip_bfloat16* __restrict__ WprojT,
                 __hip_bfloat16* __restrict__ Wb1T) {
    __shared__ float shm[32 * 33];
    int bid = blockIdx.x, tid = threadIdx.x;
    if (bid < NT1) { do_transpose(Wqkv, WqkvT, Dc, TD, bid % 72, bid / 72, tid, shm); return; }
    bid -= NT1;
    if (bid < NT2) { do_transpose(Wproj, WprojT, Dc, Dc, bid % 24, bid / 24, tid, shm); return; }
    bid -= NT2;
    if (bid < NT3) { do_transpose(Wb1, Wb1T, Dc, Rc, bid % 4, bid / 4, tid, shm); return; }
    bid -= NT3;
    // LayerNorm row
    int row = bid;
    const float* xr = x + (size_t)row * Dc;
    __hip_bfloat16* yr = xnb + (size_t)row * Dc;
    __hip_bfloat16* xbr = xb + (size_t)row * Dc;
    float v[3];
    float s = 0.f;
#pragma unroll
    for (int i = 0; i < 3; i++) { v[i] = xr[tid + i * 256]; s += v[i]; }
    shm[tid] = s; __syncthreads();
    for (int off = 128; off > 0; off >>= 1) {
        if (tid < off) shm[tid] += shm[tid + off];
        __syncthreads();
    }
    float mu = shm[0] / (float)Dc;
    __syncthreads();
    float s2 = 0.f;
#pragma unroll
    for (int i = 0; i < 3; i++) { float d = v[i] - mu; s2 += d * d; }
    shm[tid] = s2; __syncthreads();
    for (int off = 128; off > 0; off >>= 1) {
        if (tid < off) shm[tid] += shm[tid + off];
        __syncthreads();
    }
    float rstd = rsqrtf(shm[0] / (float)Dc + 1e-5f);
#pragma unroll
    for (int i = 0; i < 3; i++) {
        int c = tid + i * 256;
        yr[c] = __float2bfloat16((v[i] - mu) * rstd * ln_w[c] + ln_b[c]);
        xbr[c] = __float2bfloat16(v[i]);
    }
}

// ---------------- Fat GEMM: 128x64 tiles, 4 waves, 608 blocks (qkv 576 + bneck 32) ----------------
constexpr int NQB = (BL / 128) * (TD / 64);    // 576
constexpr int NFAT = NQB + (BL / 128) * 2;     // 608
__global__ __launch_bounds__(256)
void fat_gemm_kernel(const __hip_bfloat16* __restrict__ A1,
                     const __hip_bfloat16* __restrict__ B1,
                     const float* __restrict__ bias1,
                     __hip_bfloat16* __restrict__ C1,
                     const __hip_bfloat16* __restrict__ A2,
                     const __hip_bfloat16* __restrict__ B2,
                     float* __restrict__ C2) {
    __shared__ short lds[2][128 * 64 + 64 * 64];   // A tile then B tile, 24 KB/buf
    int bid = blockIdx.x;
    bid = (bid & 7) * (NFAT / 8) + (bid >> 3);     // bijective: 608 % 8 == 0
    bool isq = bid < NQB;
    int bx, by, N;
    const __hip_bfloat16 *A, *BT;
    if (isq) { bx = bid % 36; by = bid / 36; A = A1; BT = B1; N = TD; }
    else     { int b2 = bid - NQB; bx = b2 % 2; by = b2 / 2; A = A2; BT = B2; N = Rc; }
    const int K = Dc;

    int tid = threadIdx.x;
    int wave = tid >> 6, lane = tid & 63;
    int l16 = lane & 15, l4 = lane >> 4;
    int m0 = by * 128, n0 = bx * 64;

    int r_in = lane >> 3;                     // 0..7
    int s_src = (lane & 7) ^ r_in;            // inverse-swizzled source slot
    const __hip_bfloat16* gsrcA = A  + (size_t)(m0 + wave * 32 + r_in) * K + s_src * 8;
    const __hip_bfloat16* gsrcB = BT + (size_t)(n0 + wave * 16 + r_in) * K + s_src * 8;

    int wr = (wave >> 1) * 64, wc = (wave & 1) * 32;
    int xs = l16 & 7;                         // read-side XOR (== row & 7)

    f32x4 acc[4][2];
#pragma unroll
    for (int i = 0; i < 4; i++)
#pragma unroll
        for (int j = 0; j < 2; j++) acc[i][j] = f32x4{0.f, 0.f, 0.f, 0.f};

    auto stage = [&](int buf, int kt) {
        short* lbA = &lds[buf][(wave * 32) * 64];
        short* lbB = &lds[buf][128 * 64 + (wave * 16) * 64];
        const __hip_bfloat16* gA = gsrcA + kt * 64;
        const __hip_bfloat16* gB = gsrcB + kt * 64;
#pragma unroll
        for (int i = 0; i < 4; i++)           // A: 32 rows/wave
            GLOAD_LDS16(gA + (size_t)i * 8 * K, lbA + i * 8 * 64);
#pragma unroll
        for (int i = 0; i < 2; i++)           // B: 16 rows/wave
            GLOAD_LDS16(gB + (size_t)i * 8 * K, lbB + i * 8 * 64);
    };
    auto compute = [&](int buf) {
        const short* As = &lds[buf][0];
        const short* Bs = &lds[buf][128 * 64];
#pragma unroll
        for (int kk = 0; kk < 2; kk++) {
            bf16x8 af[4], bfr[2];
            int slot = (kk * 4 + l4) ^ xs;
#pragma unroll
            for (int f = 0; f < 4; f++)
                af[f] = *reinterpret_cast<const bf16x8*>(
                    &As[(wr + f * 16 + l16) * 64 + slot * 8]);
#pragma unroll
            for (int f = 0; f < 2; f++)
                bfr[f] = *reinterpret_cast<const bf16x8*>(
                    &Bs[(wc + f * 16 + l16) * 64 + slot * 8]);
#pragma unroll
            for (int i = 0; i < 4; i++)
#pragma unroll
                for (int j = 0; j < 2; j++)
                    acc[i][j] = __builtin_amdgcn_mfma_f32_16x16x32_bf16(
                        af[i], bfr[j], acc[i][j], 0, 0, 0);
        }
    };

    int NT = K / 64;
    int cur = 0;
    stage(0, 0);
    __syncthreads();
    for (int t = 0; t < NT; t++) {
        if (t + 1 < NT) stage(cur ^ 1, t + 1);
        compute(cur);
        if (t + 1 < NT) { __syncthreads(); cur ^= 1; }
    }

    int crow = l4 * 4;
#pragma unroll
    for (int i = 0; i < 4; i++) {
#pragma unroll
        for (int j = 0; j < 2; j++) {
            int col = n0 + wc + j * 16 + l16;
            float bb = isq ? bias1[col] : 0.f;
#pragma unroll
            for (int r = 0; r < 4; r++) {
                int rowm = m0 + wr + i * 16 + crow + r;
                float v = acc[i][j][r] + bb;
                if (isq) {
                    C1[(size_t)rowm * N + col] = __float2bfloat16(v);
                } else {
                    v = v / (1.f + expf(-v));            // silu
                    C2[(size_t)rowm * N + col] = v;
                }
            }
        }
    }
}

// ---------------- proj GEMM: 64x64 tile, 4 waves, 384 blocks ----------------
__global__ __launch_bounds__(256)
void gemm64_kernel(const __hip_bfloat16* __restrict__ A,
                   const __hip_bfloat16* __restrict__ BT,
                   const float* __restrict__ bias,
                   float* __restrict__ C, int M, int N, int K, int nbx) {
    __shared__ short lds[2][128 * 64];   // rows 0-63 = A, 64-127 = B
    int nwg = gridDim.x;
    int bid = blockIdx.x;
    if ((nwg & 7) == 0) bid = (bid & 7) * (nwg >> 3) + (bid >> 3);
    int m0 = (bid / nbx) * 64, n0 = (bid % nbx) * 64;

    int tid = threadIdx.x;
    int wave = tid >> 6, lane = tid & 63;
    int l16 = lane & 15, l4 = lane >> 4;

    int r_in = lane >> 3;
    int s_src = (lane & 7) ^ r_in;
    const __hip_bfloat16* gsrc = (wave < 2)
        ? A  + (size_t)(m0 + wave * 32 + r_in) * K + s_src * 8
        : BT + (size_t)(n0 + (wave - 2) * 32 + r_in) * K + s_src * 8;

    int wr = (wave >> 1) * 32, wc = (wave & 1) * 32;
    int xs = l16 & 7;

    f32x4 acc[2][2];
#pragma unroll
    for (int i = 0; i < 2; i++)
#pragma unroll
        for (int j = 0; j < 2; j++) acc[i][j] = f32x4{0.f, 0.f, 0.f, 0.f};

    auto stage = [&](int buf, int kt) {
        const __hip_bfloat16* g = gsrc + kt * 64;
        short* lb = &lds[buf][wave * 32 * 64];
#pragma unroll
        for (int i = 0; i < 4; i++)
            GLOAD_LDS16(g + (size_t)i * 8 * K, lb + i * 8 * 64);
    };
    auto compute = [&](int buf) {
        const short* As = &lds[buf][0];
        const short* Bs = &lds[buf][64 * 64];
#pragma unroll
        for (int kk = 0; kk < 2; kk++) {
            bf16x8 af[2], bfr[2];
            int slot = (kk * 4 + l4) ^ xs;
#pragma unroll
            for (int f = 0; f < 2; f++) {
                af[f]  = *reinterpret_cast<const bf16x8*>(
                    &As[(wr + f * 16 + l16) * 64 + slot * 8]);
                bfr[f] = *reinterpret_cast<const bf16x8*>(
                    &Bs[(wc + f * 16 + l16) * 64 + slot * 8]);
            }
#pragma unroll
            for (int i = 0; i < 2; i++)
#pragma unroll
                for (int j = 0; j < 2; j++)
                    acc[i][j] = __builtin_amdgcn_mfma_f32_16x16x32_bf16(
                        af[i], bfr[j], acc[i][j], 0, 0, 0);
        }
    };

    int NT = K / 64;
    int cur = 0;
    stage(0, 0);
    __syncthreads();
    for (int t = 0; t < NT; t++) {
        if (t + 1 < NT) stage(cur ^ 1, t + 1);
        compute(cur);
        if (t + 1 < NT) { __syncthreads(); cur ^= 1; }
    }

    int crow = l4 * 4;
#pragma unroll
    for (int i = 0; i < 2; i++) {
#pragma unroll
        for (int j = 0; j < 2; j++) {
            int col = n0 + wc + j * 16 + l16;
            float bb = bias[col];
#pragma unroll
            for (int r = 0; r < 4; r++) {
                int rowm = m0 + wr + i * 16 + crow + r;
                C[(size_t)rowm * N + col] = acc[i][j][r] + bb;
            }
        }
    }
}

// ---------------- Phase A (MFMA) + fused gate + last-arriver chunk prefix ----------------
constexpr int LQ = 72;    // padded row stride (shorts) for 64-col bf16 tiles
__global__ __launch_bounds__(256)
void phaseA_kernel(const __hip_bfloat16* __restrict__ qkv, const float* __restrict__ tbuf,
                   const float* __restrict__ Wb2, const float* __restrict__ temperature,
                   float* __restrict__ gate_out,
                   float* __restrict__ SU, float* __restrict__ zc,
                   unsigned* __restrict__ cnt) {
    int bid = blockIdx.x;           // bh*16 + c
    int bh = bid >> 4, c = bid & 15;
    int b = bh / Hc, h = bh % Hc;
    int tok0 = b * Lc + c * CH;
    __shared__ short KsT[64 * LQ];  // [d][t]
    __shared__ short VT[80 * LQ];   // [e][t]; row 64 = ones (-> zc); 65..79 = 0
    __shared__ float w2s[5 * 128];  // Wb2 head slice, [c][r]
    __shared__ float ogs[64];
    __shared__ unsigned lastFlag;
    int tid = threadIdx.x;
    int wave = tid >> 6, lane = tid & 63;
    int l16 = lane & 15, l4 = lane >> 4;

    // stage Wb2 head slice [c][r]
    for (int i = tid; i < 640; i += 256) {
        int cc = i >> 7, r = i & 127;
        w2s[i] = Wb2[r * (Hc * 5) + h * 5 + cc];
    }
    // load k/v into regs early (overlaps gate compute)
    bf16x8 k8[2], v8[2];
#pragma unroll
    for (int i = 0; i < 2; i++) {
        int c8 = tid + i * 256;
        int tt = c8 >> 3, d8 = (c8 & 7) * 8;
        size_t rowoff = (size_t)(tok0 + tt) * TD + h * dh;
        k8[i] = *reinterpret_cast<const bf16x8*>(qkv + rowoff + Dc + d8);
        v8[i] = *reinterpret_cast<const bf16x8*>(qkv + rowoff + 2 * Dc + d8);
    }
    // zero VT rows 64..79, then set ones row
    for (int i = tid; i < 16 * LQ; i += 256) VT[64 * LQ + i] = 0;
    if (tid < 64) VT[64 * LQ + tid] = f2b(1.0f);
    __syncthreads();   // w2s ready

    // gate: 4 lanes per token, 32 R-values each; shfl reduce
    {
        int tt = tid >> 2, sub = tid & 3;
        const float* tr = tbuf + (size_t)(tok0 + tt) * Rc + sub * 32;
        float p[5] = {};
        for (int r4 = 0; r4 < 32; r4 += 4) {
            float4 tv = *reinterpret_cast<const float4*>(tr + r4);
#pragma unroll
            for (int cc = 0; cc < 5; cc++) {
                float4 w4 = *reinterpret_cast<const float4*>(&w2s[cc * 128 + sub * 32 + r4]);
                p[cc] = fmaf(tv.x, w4.x, fmaf(tv.y, w4.y,
                        fmaf(tv.z, w4.z, fmaf(tv.w, w4.w, p[cc]))));
            }
        }
#pragma unroll
        for (int cc = 0; cc < 5; cc++) {
            p[cc] += __shfl_xor(p[cc], 1, 64);
            p[cc] += __shfl_xor(p[cc], 2, 64);
        }
        if (sub == 0) {
            const float PI = 3.14159265358979323846f;
            float sem_amp = 1.f / (1.f + expf(-p[0]));
            float sem_phase = tanhf(p[1]) * PI;
            float ctx_amp = 1.f / (1.f + expf(-p[2]));
            float ctx_phase = tanhf(p[3]) * PI;
            float temp = fminf(fmaxf(temperature[0], 0.1f), 2.0f);
            float inter = tanhf(sem_amp * ctx_amp * cosf(sem_phase - ctx_phase)) * temp;
            float g = 1.f / (1.f + expf(-inter));
            gate_out[(size_t)(tok0 + tt) * Hc + h] = g;
            ogs[tt] = 1.f + g;
        }
    }
    __syncthreads();   // ogs ready

    // transposed LDS writes: KsT[d][t], VT[e][t]
#pragma unroll
    for (int i = 0; i < 2; i++) {
        int c8 = tid + i * 256;
        int tt = c8 >> 3, d8 = (c8 & 7) * 8;
        float gv = ogs[tt];
#pragma unroll
        for (int j = 0; j < 8; j++) {
            float kv = bf2f(k8[i][j]);
            KsT[(d8 + j) * LQ + tt] = f2b(kv > 0.f ? kv + 1.f : expf(kv));
            VT[(d8 + j) * LQ + tt]  = f2b(bf2f(v8[i][j]) * gv);
        }
    }
    __syncthreads();

    // U[d][e] = sum_t K[t][d] * Vog[t][e]  (+ col e=64 -> zc[d])
    const short* arow = &KsT[(wave * 16 + l16) * LQ];
    f32x4 acc[5];
#pragma unroll
    for (int j = 0; j < 5; j++) acc[j] = f32x4{0.f, 0.f, 0.f, 0.f};
#pragma unroll
    for (int kk = 0; kk < 2; kk++) {
        bf16x8 af = *reinterpret_cast<const bf16x8*>(&arow[kk * 32 + l4 * 8]);
#pragma unroll
        for (int j = 0; j < 5; j++) {
            bf16x8 bfv = *reinterpret_cast<const bf16x8*>(
                &VT[(j * 16 + l16) * LQ + kk * 32 + l4 * 8]);
            acc[j] = __builtin_amdgcn_mfma_f32_16x16x32_bf16(af, bfv, acc[j], 0, 0, 0);
        }
    }
    int dbase = wave * 16 + l4 * 4;
    float* SUo = SU + (size_t)bid * 4096;
#pragma unroll
    for (int j = 0; j < 4; j++) {
        int e = j * 16 + l16;
#pragma unroll
        for (int r = 0; r < 4; r++)
            SUo[e * 64 + dbase + r] = acc[j][r];
    }
    if (l16 == 0) {
#pragma unroll
        for (int r = 0; r < 4; r++)
            zc[bid * 64 + dbase + r] = acc[4][r];
    }

    // ---- last-arriver for this bh performs the exclusive chunk prefix ----
    __syncthreads();                       // drains all global stores (vmcnt 0)
    if (tid == 0) {
        __threadfence();                   // release: writeback this XCD's L2
        lastFlag = (atomicAdd(&cnt[bh], 1u) == NC - 1) ? 1u : 0u;
    }
    __syncthreads();
    if (lastFlag == 0) return;
    __threadfence();                       // acquire: invalidate stale lines
    {
        float* S = SU + (size_t)bh * NC * 4096;
        for (int i = tid; i < 4096; i += 256) {
            float r[NC];
#pragma unroll
            for (int cc = 0; cc < NC; cc++) r[cc] = S[cc * 4096 + i];
            float run = 0.f;
#pragma unroll
            for (int cc = 0; cc < NC; cc++) { S[cc * 4096 + i] = run; run += r[cc]; }
        }
        if (tid < 64) {
            float* z = zc + (size_t)bh * NC * 64 + tid;
            float r[NC];
#pragma unroll
            for (int cc = 0; cc < NC; cc++) r[cc] = z[cc * 64];
            float run = 0.f;
#pragma unroll
            for (int cc = 0; cc < NC; cc++) { z[cc * 64] = run; run += r[cc]; }
        }
    }
}

// ---------------- Phase C: MFMA per-chunk output + mini-LN, bf16 out ----------------
constexpr int LB = 136;   // padded row stride for 128-col bf16 B-tile
__global__ __launch_bounds__(256)
void phaseC_kernel(const __hip_bfloat16* __restrict__ qkv, const float* __restrict__ gate,
                   const float* __restrict__ SU, const float* __restrict__ zc,
                   const float* __restrict__ mn_w, const float* __restrict__ mn_b,
                   __hip_bfloat16* __restrict__ attn) {
    int bid = blockIdx.x;           // bh*16 + c
    int bh = bid >> 4;
    int b = bh / Hc, h = bh % Hc;
    int tok0 = b * Lc + (bid & 15) * CH;
    __shared__ short Qs[64 * LQ];   // q_f  [l][d]
    __shared__ short Ks[64 * LQ];   // k_f  [t][d]
    __shared__ short Ps[64 * LQ];   // masked P [l][t]
    __shared__ short Bst[80 * LB];  // rows e: [V^T*og | S^T]; row64 = [1 | z_start]; 65..79 = 0
    int tid = threadIdx.x;
    int wave = tid >> 6, lane = tid & 63;
    int l16 = lane & 15, l4 = lane >> 4;

    const float* SUp = SU + (size_t)bid * 4096;   // prefixed, [e][d]
    const float* zcp = zc + (size_t)bid * 64;     // prefixed z_start

#pragma unroll
    for (int i = 0; i < 2; i++) {
        int c8 = tid + i * 256;
        int tt = c8 >> 3, d8 = (c8 & 7) * 8;
        size_t rowoff = (size_t)(tok0 + tt) * TD + h * dh;
        bf16x8 q8 = *reinterpret_cast<const bf16x8*>(qkv + rowoff + d8);
        bf16x8 k8 = *reinterpret_cast<const bf16x8*>(qkv + rowoff + Dc + d8);
        bf16x8 v8 = *reinterpret_cast<const bf16x8*>(qkv + rowoff + 2 * Dc + d8);
        float gv = 1.f + gate[(size_t)(tok0 + tt) * Hc + h];
        short qo[8], ko[8];
#pragma unroll
        for (int j = 0; j < 8; j++) {
            float qv = bf2f(q8[j]);
            qo[j] = f2b(qv > 0.f ? qv + 1.f : expf(qv));
            float kv = bf2f(k8[j]);
            ko[j] = f2b(kv > 0.f ? kv + 1.f : expf(kv));
            Bst[(d8 + j) * LB + tt] = f2b(bf2f(v8[j]) * gv);   // V^T transpose write
        }
        *reinterpret_cast<bf16x8*>(&Qs[tt * LQ + d8]) = *reinterpret_cast<bf16x8*>(qo);
        *reinterpret_cast<bf16x8*>(&Ks[tt * LQ + d8]) = *reinterpret_cast<bf16x8*>(ko);
        float4 sa = *reinterpret_cast<const float4*>(SUp + tt * 64 + d8);
        float4 sb = *reinterpret_cast<const float4*>(SUp + tt * 64 + d8 + 4);
        short so[8] = { f2b(sa.x), f2b(sa.y), f2b(sa.z), f2b(sa.w),
                        f2b(sb.x), f2b(sb.y), f2b(sb.z), f2b(sb.w) };
        *reinterpret_cast<bf16x8*>(&Bst[tt * LB + 64 + d8]) = *reinterpret_cast<bf16x8*>(so);
    }
    if (tid < 64) {
        Bst[64 * LB + tid] = f2b(1.0f);          // ones -> row-sum of P (den part 1)
        Bst[64 * LB + 64 + tid] = f2b(zcp[tid]); // z_start -> q.z (den part 2)
    } else {
        for (int i2 = tid - 64; i2 < 15 * LB; i2 += 192) Bst[65 * LB + i2] = 0;
    }
    __syncthreads();   // barrier 1

    // ---- P = Qf Kf^T : wave owns l-strip [wave*16, wave*16+16) ----
    const short* arow = &Qs[(wave * 16 + l16) * LQ];
    f32x4 accp[4];
#pragma unroll
    for (int j = 0; j < 4; j++) accp[j] = f32x4{0.f, 0.f, 0.f, 0.f};
#pragma unroll
    for (int kk = 0; kk < 2; kk++) {
        bf16x8 af = *reinterpret_cast<const bf16x8*>(&arow[kk * 32 + l4 * 8]);
#pragma unroll
        for (int j = 0; j < 4; j++) {
            bf16x8 bfv = *reinterpret_cast<const bf16x8*>(
                &Ks[(j * 16 + l16) * LQ + kk * 32 + l4 * 8]);
            accp[j] = __builtin_amdgcn_mfma_f32_16x16x32_bf16(af, bfv, accp[j], 0, 0, 0);
        }
    }
#pragma unroll
    for (int j = 0; j < 4; j++) {
#pragma unroll
        for (int r = 0; r < 4; r++) {
            int l = wave * 16 + l4 * 4 + r;
            int t = j * 16 + l16;
            float pv = (t <= l) ? accp[j][r] : 0.f;
            Ps[l * LQ + t] = f2b(pv);
        }
    }
    __syncthreads();   // barrier 2

    // ---- O = [P | Qf] @ Bst^T : 5 e-tiles (j=4 col 64 = den) ----
    const short* prow = &Ps[(wave * 16 + l16) * LQ];
    f32x4 acc[5];
#pragma unroll
    for (int j = 0; j < 5; j++) acc[j] = f32x4{0.f, 0.f, 0.f, 0.f};
#pragma unroll
    for (int kk = 0; kk < 4; kk++) {
        bf16x8 af = (kk < 2)
            ? *reinterpret_cast<const bf16x8*>(&prow[kk * 32 + l4 * 8])
            : *reinterpret_cast<const bf16x8*>(&arow[(kk - 2) * 32 + l4 * 8]);
#pragma unroll
        for (int j = 0; j < 5; j++) {
            bf16x8 bfv = *reinterpret_cast<const bf16x8*>(
                &Bst[(j * 16 + l16) * LB + kk * 32 + l4 * 8]);
            acc[j] = __builtin_amdgcn_mfma_f32_16x16x32_bf16(af, bfv, acc[j], 0, 0, 0);
        }
    }

    // ---- epilogue: den, mini-LN over e (in-register, shfl over l16 group) ----
#pragma unroll
    for (int r = 0; r < 4; r++) {
        float den = __shfl(acc[4][r], l4 * 16) + 1e-6f;
        float inv = 1.f / den;
        float v0 = acc[0][r] * inv, v1 = acc[1][r] * inv;
        float v2 = acc[2][r] * inv, v3 = acc[3][r] * inv;
        float s1 = v0 + v1 + v2 + v3;
        float s2 = v0 * v0 + v1 * v1 + v2 * v2 + v3 * v3;
#pragma unroll
        for (int m = 1; m < 16; m <<= 1) {
            s1 += __shfl_xor(s1, m, 64);
            s2 += __shfl_xor(s2, m, 64);
        }
        float mu = s1 * (1.f / 64.f);
        float rstd = rsqrtf(s2 * (1.f / 64.f) - mu * mu + 1e-5f);
        int l = wave * 16 + l4 * 4 + r;
        __hip_bfloat16* orow = attn + (size_t)(tok0 + l) * Dc + h * dh;
        float vj[4] = {v0, v1, v2, v3};
#pragma unroll
        for (int j = 0; j < 4; j++) {
            int e = j * 16 + l16;
            orow[e] = __float2bfloat16((vj[j] - mu) * rstd * mn_w[e] + mn_b[e]);
        }
    }
}

extern "C" void kernel_launch(void* const* d_in, const int* in_sizes, int n_in,
                              void* d_out, int out_size, void* d_ws, size_t ws_size,
                              hipStream_t stream) {
    const float* x     = (const float*)d_in[0];
    const float* Wqkv  = (const float*)d_in[1];
    const float* bqkv  = (const float*)d_in[2];
    const float* Wb1   = (const float*)d_in[3];
    const float* Wb2   = (const float*)d_in[4];
    const float* temp  = (const float*)d_in[5];
    const float* Wproj = (const float*)d_in[6];
    const float* bproj = (const float*)d_in[7];
    const float* ln_w  = (const float*)d_in[8];
    const float* ln_b  = (const float*)d_in[9];
    const float* mn_w  = (const float*)d_in[10];
    const float* mn_b  = (const float*)d_in[11];

    float* out0 = (float*)d_out;                 // [2048, 768]
    float* gate = out0 + (size_t)BL * Dc;        // [2048, 12]

    unsigned* cnt = (unsigned*)d_ws;             // 64 u32 counter space
    float* tbuf = (float*)d_ws + 64;             // 2048*128 f32
    float* SU   = tbuf + (size_t)BL * Rc;        // 24*16*4096 f32 (U^T, [e][d])
    float* zc   = SU + (size_t)BH * NC * 4096;   // 24*16*64 f32
    __hip_bfloat16* bfr = (__hip_bfloat16*)(zc + (size_t)BH * NC * 64);
    __hip_bfloat16* qkvb   = bfr;                        // 2048*2304 bf16
    __hip_bfloat16* xnb    = qkvb + (size_t)BL * TD;     // 2048*768 bf16
    __hip_bfloat16* xb     = xnb + (size_t)BL * Dc;      // 2048*768 bf16 (raw x)
    __hip_bfloat16* attnb  = xb + (size_t)BL * Dc;       // 2048*768 bf16
    __hip_bfloat16* WqkvT  = attnb + (size_t)BL * Dc;    // 2304*768 bf16
    __hip_bfloat16* WprojT = WqkvT + (size_t)TD * Dc;    // 768*768 bf16
    __hip_bfloat16* Wb1T   = WprojT + (size_t)Dc * Dc;   // 128*768 bf16

    // 0. zero the per-bh completion counters (graph-capturable memset node)
    hipMemsetAsync(cnt, 0, 256, stream);
    // 1. prep: weight transposes + LayerNorm
    prep_kernel<<<NPREP, 256, 0, stream>>>(x, ln_w, ln_b, Wqkv, Wproj, Wb1,
                                           xnb, xb, WqkvT, WprojT, Wb1T);
    // 2. fat dispatch: qkv GEMM (bf16 out) + bottleneck silu GEMM (fp32 out)
    fat_gemm_kernel<<<NFAT, 256, 0, stream>>>(xnb, WqkvT, bqkv, qkvb, xb, Wb1T, tbuf);
    // 3. phaseA (MFMA): per-chunk U^T + z sums + fused gate + last-arriver prefix
    phaseA_kernel<<<BH * NC, 256, 0, stream>>>(qkvb, tbuf, Wb2, temp, gate, SU, zc, cnt);
    // 4. per-chunk outputs (MFMA) + mini-LN -> bf16
    phaseC_kernel<<<BH * NC, 256, 0, stream>>>(qkvb, gate, SU, zc, mn_w, mn_b, attnb);
    // 5. out0 = attn @ Wproj + bproj  (64x64-tile MFMA, 384 blocks)
    gemm64_kernel<<<(BL / 64) * (Dc / 64), 256, 0, stream>>>(
        attnb, WprojT, bproj, out0, BL, Dc, Dc, Dc / 64);
}

// Round 13
// 58.144 us; speedup vs baseline: 3.0201x; 1.7729x over previous
//
#include <hip/hip_runtime.h>
#include <hip/hip_bf16.h>
#include <math.h>

// Problem constants
constexpr int Bc = 2, Lc = 1024, Dc = 768, Hc = 12, dh = 64, Rc = 128;
constexpr int BL = Bc * Lc;          // 2048 tokens
constexpr int TD = 3 * Dc;           // 2304
constexpr int CH = 64;               // chunk length
constexpr int NC = Lc / CH;          // 16 chunks per sequence
constexpr int BH = Bc * Hc;          // 24

typedef __attribute__((ext_vector_type(8))) short bf16x8;
typedef __attribute__((ext_vector_type(4))) float f32x4;

__device__ __forceinline__ float bf2f(short u) {
    union { float f; unsigned int i; } c;
    c.i = ((unsigned int)(unsigned short)u) << 16;
    return c.f;
}
__device__ __forceinline__ short f2b(float f) {
    __hip_bfloat16 h = __float2bfloat16(f);
    return *reinterpret_cast<short*>(&h);
}

#define GLOAD_LDS16(gp, lp)                                                        \
    __builtin_amdgcn_global_load_lds(                                              \
        (const __attribute__((address_space(1))) void*)(gp),                       \
        (__attribute__((address_space(3))) void*)(lp), 16, 0, 0)

// ---------------- Prep: 3 weight transposes + LayerNorm, one kernel ----------------
__device__ __forceinline__ void do_transpose(const float* __restrict__ W,
                                             __hip_bfloat16* __restrict__ WT,
                                             int K, int N, int bx, int by,
                                             int tid, float* t) {
    int k0 = by * 32, n0 = bx * 32;
    int r = tid >> 5, c = tid & 31;   // r in 0..7
#pragma unroll
    for (int i = 0; i < 4; i++)
        t[(r + i * 8) * 33 + c] = W[(size_t)(k0 + r + i * 8) * N + n0 + c];
    __syncthreads();
#pragma unroll
    for (int i = 0; i < 4; i++)
        WT[(size_t)(n0 + r + i * 8) * K + k0 + c] = __float2bfloat16(t[c * 33 + r + i * 8]);
}

constexpr int NT1 = (TD / 32) * (Dc / 32);   // 1728  Wqkv
constexpr int NT2 = (Dc / 32) * (Dc / 32);   // 576   Wproj
constexpr int NT3 = (Rc / 32) * (Dc / 32);   // 96    Wb1
constexpr int NPREP = NT1 + NT2 + NT3 + BL;  // + 2048 LN rows

__global__ __launch_bounds__(256)
void prep_kernel(const float* __restrict__ x, const float* __restrict__ ln_w,
                 const float* __restrict__ ln_b,
                 const float* __restrict__ Wqkv, const float* __restrict__ Wproj,
                 const float* __restrict__ Wb1,
                 __hip_bfloat16* __restrict__ xnb, __hip_bfloat16* __restrict__ xb,
                 __hip_bfloat16* __restrict__ WqkvT, __hip_bfloat16* __restrict__ WprojT,
                 __hip_bfloat16* __restrict__ Wb1T) {
    __shared__ float shm[32 * 33];
    int bid = blockIdx.x, tid = threadIdx.x;
    if (bid < NT1) { do_transpose(Wqkv, WqkvT, Dc, TD, bid % 72, bid / 72, tid, shm); return; }
    bid -= NT1;
    if (bid < NT2) { do_transpose(Wproj, WprojT, Dc, Dc, bid % 24, bid / 24, tid, shm); return; }
    bid -= NT2;
    if (bid < NT3) { do_transpose(Wb1, Wb1T, Dc, Rc, bid % 4, bid / 4, tid, shm); return; }
    bid -= NT3;
    // LayerNorm row
    int row = bid;
    const float* xr = x + (size_t)row * Dc;
    __hip_bfloat16* yr = xnb + (size_t)row * Dc;
    __hip_bfloat16* xbr = xb + (size_t)row * Dc;
    float v[3];
    float s = 0.f;
#pragma unroll
    for (int i = 0; i < 3; i++) { v[i] = xr[tid + i * 256]; s += v[i]; }
    shm[tid] = s; __syncthreads();
    for (int off = 128; off > 0; off >>= 1) {
        if (tid < off) shm[tid] += shm[tid + off];
        __syncthreads();
    }
    float mu = shm[0] / (float)Dc;
    __syncthreads();
    float s2 = 0.f;
#pragma unroll
    for (int i = 0; i < 3; i++) { float d = v[i] - mu; s2 += d * d; }
    shm[tid] = s2; __syncthreads();
    for (int off = 128; off > 0; off >>= 1) {
        if (tid < off) shm[tid] += shm[tid + off];
        __syncthreads();
    }
    float rstd = rsqrtf(shm[0] / (float)Dc + 1e-5f);
#pragma unroll
    for (int i = 0; i < 3; i++) {
        int c = tid + i * 256;
        yr[c] = __float2bfloat16((v[i] - mu) * rstd * ln_w[c] + ln_b[c]);
        xbr[c] = __float2bfloat16(v[i]);
    }
}

// ---------------- Fat GEMM dispatch: qkv (288 blocks) + bottleneck silu (16 blocks) ----------------
constexpr int NQB = (TD / 128) * (BL / 128);   // 288
constexpr int NFAT = NQB + BL / 128;           // 304
__global__ __launch_bounds__(512)
void fat_gemm_kernel(const __hip_bfloat16* __restrict__ A1,
                     const __hip_bfloat16* __restrict__ B1,
                     const float* __restrict__ bias1,
                     __hip_bfloat16* __restrict__ C1,
                     const __hip_bfloat16* __restrict__ A2,
                     const __hip_bfloat16* __restrict__ B2,
                     float* __restrict__ C2) {
    __shared__ short lds[2][2][128 * 64];
    int bid = blockIdx.x;
    bid = (bid & 7) * (NFAT / 8) + (bid >> 3);          // bijective: 304 % 8 == 0
    bool isq = bid < NQB;
    int bx, by, N;
    const __hip_bfloat16 *A, *BT;
    if (isq) { bx = bid % 18; by = bid / 18; A = A1; BT = B1; N = TD; }
    else     { int b2 = bid - NQB; bx = 0; by = b2; A = A2; BT = B2; N = Rc; }
    const int K = Dc;

    int tid = threadIdx.x;
    int wave = tid >> 6, lane = tid & 63;
    int l16 = lane & 15, l4 = lane >> 4;
    int m0 = by * 128, n0 = bx * 128;

    int ab = wave >> 2;
    int r_in = lane >> 3;
    int s_src = (lane & 7) ^ r_in;
    const __hip_bfloat16* gbase = ab ? (BT + (size_t)n0 * K) : (A + (size_t)m0 * K);
    const __hip_bfloat16* gsrc =
        gbase + (size_t)((wave & 3) * 32 + r_in) * K + s_src * 8;

    int wr = (wave >> 2) * 64, wc = (wave & 3) * 32;
    int xs = l16 & 7;

    f32x4 acc[4][2];
#pragma unroll
    for (int i = 0; i < 4; i++)
#pragma unroll
        for (int j = 0; j < 2; j++) acc[i][j] = f32x4{0.f, 0.f, 0.f, 0.f};

    auto stage = [&](int buf, int kt) {
        const __hip_bfloat16* g = gsrc + kt * 64;
        short* lb = &lds[buf][ab][(wave & 3) * 32 * 64];
#pragma unroll
        for (int i = 0; i < 4; i++)
            GLOAD_LDS16(g + (size_t)i * 8 * K, lb + i * 8 * 64);
    };
    auto compute = [&](int buf) {
        const short* As = &lds[buf][0][0];
        const short* Bs = &lds[buf][1][0];
#pragma unroll
        for (int kk = 0; kk < 2; kk++) {
            bf16x8 af[4], bfr[2];
            int slot = (kk * 4 + l4) ^ xs;
#pragma unroll
            for (int f = 0; f < 4; f++)
                af[f] = *reinterpret_cast<const bf16x8*>(
                    &As[(wr + f * 16 + l16) * 64 + slot * 8]);
#pragma unroll
            for (int f = 0; f < 2; f++)
                bfr[f] = *reinterpret_cast<const bf16x8*>(
                    &Bs[(wc + f * 16 + l16) * 64 + slot * 8]);
#pragma unroll
            for (int i = 0; i < 4; i++)
#pragma unroll
                for (int j = 0; j < 2; j++)
                    acc[i][j] = __builtin_amdgcn_mfma_f32_16x16x32_bf16(
                        af[i], bfr[j], acc[i][j], 0, 0, 0);
        }
    };

    int NT = K / 64;
    int cur = 0;
    stage(0, 0);
    __syncthreads();
    for (int t = 0; t < NT; t++) {
        if (t + 1 < NT) stage(cur ^ 1, t + 1);
        compute(cur);
        if (t + 1 < NT) { __syncthreads(); cur ^= 1; }
    }

    int crow = l4 * 4;
#pragma unroll
    for (int i = 0; i < 4; i++) {
#pragma unroll
        for (int j = 0; j < 2; j++) {
            int col = n0 + wc + j * 16 + l16;
            float bb = isq ? bias1[col] : 0.f;
#pragma unroll
            for (int r = 0; r < 4; r++) {
                int rowm = m0 + wr + i * 16 + crow + r;
                float v = acc[i][j][r] + bb;
                if (isq) {
                    C1[(size_t)rowm * N + col] = __float2bfloat16(v);
                } else {
                    v = v / (1.f + expf(-v));            // silu
                    C2[(size_t)rowm * N + col] = v;
                }
            }
        }
    }
}

// ---------------- proj GEMM: 64x64 tile, 4 waves, 384 blocks (occupancy) ----------------
__global__ __launch_bounds__(256)
void gemm64_kernel(const __hip_bfloat16* __restrict__ A,
                   const __hip_bfloat16* __restrict__ BT,
                   const float* __restrict__ bias,
                   float* __restrict__ C, int M, int N, int K, int nbx) {
    __shared__ short lds[2][128 * 64];   // rows 0-63 = A, 64-127 = B
    int nwg = gridDim.x;
    int bid = blockIdx.x;
    if ((nwg & 7) == 0) bid = (bid & 7) * (nwg >> 3) + (bid >> 3);
    int m0 = (bid / nbx) * 64, n0 = (bid % nbx) * 64;

    int tid = threadIdx.x;
    int wave = tid >> 6, lane = tid & 63;
    int l16 = lane & 15, l4 = lane >> 4;

    int r_in = lane >> 3;
    int s_src = (lane & 7) ^ r_in;
    const __hip_bfloat16* gsrc = (wave < 2)
        ? A  + (size_t)(m0 + wave * 32 + r_in) * K + s_src * 8
        : BT + (size_t)(n0 + (wave - 2) * 32 + r_in) * K + s_src * 8;

    int wr = (wave >> 1) * 32, wc = (wave & 1) * 32;
    int xs = l16 & 7;

    f32x4 acc[2][2];
#pragma unroll
    for (int i = 0; i < 2; i++)
#pragma unroll
        for (int j = 0; j < 2; j++) acc[i][j] = f32x4{0.f, 0.f, 0.f, 0.f};

    auto stage = [&](int buf, int kt) {
        const __hip_bfloat16* g = gsrc + kt * 64;
        short* lb = &lds[buf][wave * 32 * 64];
#pragma unroll
        for (int i = 0; i < 4; i++)
            GLOAD_LDS16(g + (size_t)i * 8 * K, lb + i * 8 * 64);
    };
    auto compute = [&](int buf) {
        const short* As = &lds[buf][0];
        const short* Bs = &lds[buf][64 * 64];
#pragma unroll
        for (int kk = 0; kk < 2; kk++) {
            bf16x8 af[2], bfr[2];
            int slot = (kk * 4 + l4) ^ xs;
#pragma unroll
            for (int f = 0; f < 2; f++) {
                af[f]  = *reinterpret_cast<const bf16x8*>(
                    &As[(wr + f * 16 + l16) * 64 + slot * 8]);
                bfr[f] = *reinterpret_cast<const bf16x8*>(
                    &Bs[(wc + f * 16 + l16) * 64 + slot * 8]);
            }
#pragma unroll
            for (int i = 0; i < 2; i++)
#pragma unroll
                for (int j = 0; j < 2; j++)
                    acc[i][j] = __builtin_amdgcn_mfma_f32_16x16x32_bf16(
                        af[i], bfr[j], acc[i][j], 0, 0, 0);
        }
    };

    int NT = K / 64;
    int cur = 0;
    stage(0, 0);
    __syncthreads();
    for (int t = 0; t < NT; t++) {
        if (t + 1 < NT) stage(cur ^ 1, t + 1);
        compute(cur);
        if (t + 1 < NT) { __syncthreads(); cur ^= 1; }
    }

    int crow = l4 * 4;
#pragma unroll
    for (int i = 0; i < 2; i++) {
#pragma unroll
        for (int j = 0; j < 2; j++) {
            int col = n0 + wc + j * 16 + l16;
            float bb = bias[col];
#pragma unroll
            for (int r = 0; r < 4; r++) {
                int rowm = m0 + wr + i * 16 + crow + r;
                C[(size_t)rowm * N + col] = acc[i][j][r] + bb;
            }
        }
    }
}

// ---------------- Phase A (MFMA): U_c^T stored [e][d], zc via ones-row; fused gate ----------------
constexpr int LQ = 72;    // padded row stride (shorts) for 64-col bf16 tiles
__global__ __launch_bounds__(256)
void phaseA_kernel(const __hip_bfloat16* __restrict__ qkv, const float* __restrict__ tbuf,
                   const float* __restrict__ Wb2, const float* __restrict__ temperature,
                   float* __restrict__ gate_out,
                   float* __restrict__ SU, float* __restrict__ zc) {
    int bid = blockIdx.x;           // bh*16 + c
    int bh = bid >> 4, c = bid & 15;
    int b = bh / Hc, h = bh % Hc;
    int tok0 = b * Lc + c * CH;
    __shared__ short KsT[64 * LQ];  // [d][t]
    __shared__ short VT[80 * LQ];   // [e][t]; row 64 = ones (-> zc); 65..79 = 0
    __shared__ float w2s[5 * 128];  // Wb2 head slice, [c][r]
    __shared__ float ogs[64];
    int tid = threadIdx.x;
    int wave = tid >> 6, lane = tid & 63;
    int l16 = lane & 15, l4 = lane >> 4;

    // stage Wb2 head slice [c][r]
    for (int i = tid; i < 640; i += 256) {
        int cc = i >> 7, r = i & 127;
        w2s[i] = Wb2[r * (Hc * 5) + h * 5 + cc];
    }
    // load k/v into regs early (overlaps gate compute)
    bf16x8 k8[2], v8[2];
#pragma unroll
    for (int i = 0; i < 2; i++) {
        int c8 = tid + i * 256;
        int tt = c8 >> 3, d8 = (c8 & 7) * 8;
        size_t rowoff = (size_t)(tok0 + tt) * TD + h * dh;
        k8[i] = *reinterpret_cast<const bf16x8*>(qkv + rowoff + Dc + d8);
        v8[i] = *reinterpret_cast<const bf16x8*>(qkv + rowoff + 2 * Dc + d8);
    }
    // zero VT rows 64..79, then set ones row
    for (int i = tid; i < 16 * LQ; i += 256) VT[64 * LQ + i] = 0;
    if (tid < 64) VT[64 * LQ + tid] = f2b(1.0f);
    __syncthreads();   // w2s ready

    // gate: 4 lanes per token, 32 R-values each; shfl reduce
    {
        int tt = tid >> 2, sub = tid & 3;
        const float* tr = tbuf + (size_t)(tok0 + tt) * Rc + sub * 32;
        float p[5] = {};
        for (int r4 = 0; r4 < 32; r4 += 4) {
            float4 tv = *reinterpret_cast<const float4*>(tr + r4);
#pragma unroll
            for (int cc = 0; cc < 5; cc++) {
                float4 w4 = *reinterpret_cast<const float4*>(&w2s[cc * 128 + sub * 32 + r4]);
                p[cc] = fmaf(tv.x, w4.x, fmaf(tv.y, w4.y,
                        fmaf(tv.z, w4.z, fmaf(tv.w, w4.w, p[cc]))));
            }
        }
#pragma unroll
        for (int cc = 0; cc < 5; cc++) {
            p[cc] += __shfl_xor(p[cc], 1, 64);
            p[cc] += __shfl_xor(p[cc], 2, 64);
        }
        if (sub == 0) {
            const float PI = 3.14159265358979323846f;
            float sem_amp = 1.f / (1.f + expf(-p[0]));
            float sem_phase = tanhf(p[1]) * PI;
            float ctx_amp = 1.f / (1.f + expf(-p[2]));
            float ctx_phase = tanhf(p[3]) * PI;
            float temp = fminf(fmaxf(temperature[0], 0.1f), 2.0f);
            float inter = tanhf(sem_amp * ctx_amp * cosf(sem_phase - ctx_phase)) * temp;
            float g = 1.f / (1.f + expf(-inter));
            gate_out[(size_t)(tok0 + tt) * Hc + h] = g;
            ogs[tt] = 1.f + g;
        }
    }
    __syncthreads();   // ogs ready

    // transposed LDS writes: KsT[d][t], VT[e][t]
#pragma unroll
    for (int i = 0; i < 2; i++) {
        int c8 = tid + i * 256;
        int tt = c8 >> 3, d8 = (c8 & 7) * 8;
        float gv = ogs[tt];
#pragma unroll
        for (int j = 0; j < 8; j++) {
            float kv = bf2f(k8[i][j]);
            KsT[(d8 + j) * LQ + tt] = f2b(kv > 0.f ? kv + 1.f : expf(kv));
            VT[(d8 + j) * LQ + tt]  = f2b(bf2f(v8[i][j]) * gv);
        }
    }
    __syncthreads();

    // U[d][e] = sum_t K[t][d] * Vog[t][e]  (+ col e=64 -> zc[d])
    const short* arow = &KsT[(wave * 16 + l16) * LQ];
    f32x4 acc[5];
#pragma unroll
    for (int j = 0; j < 5; j++) acc[j] = f32x4{0.f, 0.f, 0.f, 0.f};
#pragma unroll
    for (int kk = 0; kk < 2; kk++) {
        bf16x8 af = *reinterpret_cast<const bf16x8*>(&arow[kk * 32 + l4 * 8]);
#pragma unroll
        for (int j = 0; j < 5; j++) {
            bf16x8 bfv = *reinterpret_cast<const bf16x8*>(
                &VT[(j * 16 + l16) * LQ + kk * 32 + l4 * 8]);
            acc[j] = __builtin_amdgcn_mfma_f32_16x16x32_bf16(af, bfv, acc[j], 0, 0, 0);
        }
    }
    int dbase = wave * 16 + l4 * 4;
    float* SUo = SU + (size_t)bid * 4096;
#pragma unroll
    for (int j = 0; j < 4; j++) {
        int e = j * 16 + l16;
#pragma unroll
        for (int r = 0; r < 4; r++)
            SUo[e * 64 + dbase + r] = acc[j][r];
    }
    if (l16 == 0) {
#pragma unroll
        for (int r = 0; r < 4; r++)
            zc[bid * 64 + dbase + r] = acc[4][r];
    }
}

// ---------------- Phase B: exclusive prefix over chunks (one thread per element) ----------------
__global__ __launch_bounds__(256)
void prefix_kernel(float* __restrict__ SU, float* __restrict__ zc) {
    int gid = blockIdx.x * 256 + threadIdx.x;
    if (gid < BH * 4096) {
        int bh = gid >> 12, i = gid & 4095;
        float* S = SU + (size_t)bh * NC * 4096 + i;
        float r[NC];
#pragma unroll
        for (int cc = 0; cc < NC; cc++) r[cc] = S[cc * 4096];
        float run = 0.f;
#pragma unroll
        for (int cc = 0; cc < NC; cc++) { float tv = r[cc]; S[cc * 4096] = run; run += tv; }
    } else {
        int g2 = gid - BH * 4096;
        if (g2 < BH * 64) {
            int bh = g2 >> 6, i = g2 & 63;
            float* z = zc + (size_t)bh * NC * 64 + i;
            float r[NC];
#pragma unroll
            for (int cc = 0; cc < NC; cc++) r[cc] = z[cc * 64];
            float run = 0.f;
#pragma unroll
            for (int cc = 0; cc < NC; cc++) { float tv = r[cc]; z[cc * 64] = run; run += tv; }
        }
    }
}

// ---------------- Phase C: MFMA per-chunk output + mini-LN, bf16 out ----------------
constexpr int LB = 136;   // padded row stride for 128-col bf16 B-tile
__global__ __launch_bounds__(256)
void phaseC_kernel(const __hip_bfloat16* __restrict__ qkv, const float* __restrict__ gate,
                   const float* __restrict__ SU, const float* __restrict__ zc,
                   const float* __restrict__ mn_w, const float* __restrict__ mn_b,
                   __hip_bfloat16* __restrict__ attn) {
    int bid = blockIdx.x;           // bh*16 + c
    int bh = bid >> 4;
    int b = bh / Hc, h = bh % Hc;
    int tok0 = b * Lc + (bid & 15) * CH;
    __shared__ short Qs[64 * LQ];   // q_f  [l][d]
    __shared__ short Ks[64 * LQ];   // k_f  [t][d]
    __shared__ short Ps[64 * LQ];   // masked P [l][t]
    __shared__ short Bst[80 * LB];  // rows e: [V^T*og | S^T]; row64 = [1 | z_start]; 65..79 = 0
    int tid = threadIdx.x;
    int wave = tid >> 6, lane = tid & 63;
    int l16 = lane & 15, l4 = lane >> 4;

    const float* SUp = SU + (size_t)bid * 4096;   // prefixed, [e][d]
    const float* zcp = zc + (size_t)bid * 64;     // prefixed z_start

#pragma unroll
    for (int i = 0; i < 2; i++) {
        int c8 = tid + i * 256;
        int tt = c8 >> 3, d8 = (c8 & 7) * 8;
        size_t rowoff = (size_t)(tok0 + tt) * TD + h * dh;
        bf16x8 q8 = *reinterpret_cast<const bf16x8*>(qkv + rowoff + d8);
        bf16x8 k8 = *reinterpret_cast<const bf16x8*>(qkv + rowoff + Dc + d8);
        bf16x8 v8 = *reinterpret_cast<const bf16x8*>(qkv + rowoff + 2 * Dc + d8);
        float gv = 1.f + gate[(size_t)(tok0 + tt) * Hc + h];
        short qo[8], ko[8];
#pragma unroll
        for (int j = 0; j < 8; j++) {
            float qv = bf2f(q8[j]);
            qo[j] = f2b(qv > 0.f ? qv + 1.f : expf(qv));
            float kv = bf2f(k8[j]);
            ko[j] = f2b(kv > 0.f ? kv + 1.f : expf(kv));
            Bst[(d8 + j) * LB + tt] = f2b(bf2f(v8[j]) * gv);   // V^T transpose write
        }
        *reinterpret_cast<bf16x8*>(&Qs[tt * LQ + d8]) = *reinterpret_cast<bf16x8*>(qo);
        *reinterpret_cast<bf16x8*>(&Ks[tt * LQ + d8]) = *reinterpret_cast<bf16x8*>(ko);
        float4 sa = *reinterpret_cast<const float4*>(SUp + tt * 64 + d8);
        float4 sb = *reinterpret_cast<const float4*>(SUp + tt * 64 + d8 + 4);
        short so[8] = { f2b(sa.x), f2b(sa.y), f2b(sa.z), f2b(sa.w),
                        f2b(sb.x), f2b(sb.y), f2b(sb.z), f2b(sb.w) };
        *reinterpret_cast<bf16x8*>(&Bst[tt * LB + 64 + d8]) = *reinterpret_cast<bf16x8*>(so);
    }
    if (tid < 64) {
        Bst[64 * LB + tid] = f2b(1.0f);          // ones -> row-sum of P (den part 1)
        Bst[64 * LB + 64 + tid] = f2b(zcp[tid]); // z_start -> q.z (den part 2)
    } else {
        for (int i2 = tid - 64; i2 < 15 * LB; i2 += 192) Bst[65 * LB + i2] = 0;
    }
    __syncthreads();   // barrier 1

    // ---- P = Qf Kf^T : wave owns l-strip [wave*16, wave*16+16) ----
    const short* arow = &Qs[(wave * 16 + l16) * LQ];
    f32x4 accp[4];
#pragma unroll
    for (int j = 0; j < 4; j++) accp[j] = f32x4{0.f, 0.f, 0.f, 0.f};
#pragma unroll
    for (int kk = 0; kk < 2; kk++) {
        bf16x8 af = *reinterpret_cast<const bf16x8*>(&arow[kk * 32 + l4 * 8]);
#pragma unroll
        for (int j = 0; j < 4; j++) {
            bf16x8 bfv = *reinterpret_cast<const bf16x8*>(
                &Ks[(j * 16 + l16) * LQ + kk * 32 + l4 * 8]);
            accp[j] = __builtin_amdgcn_mfma_f32_16x16x32_bf16(af, bfv, accp[j], 0, 0, 0);
        }
    }
#pragma unroll
    for (int j = 0; j < 4; j++) {
#pragma unroll
        for (int r = 0; r < 4; r++) {
            int l = wave * 16 + l4 * 4 + r;
            int t = j * 16 + l16;
            float pv = (t <= l) ? accp[j][r] : 0.f;
            Ps[l * LQ + t] = f2b(pv);
        }
    }
    __syncthreads();   // barrier 2

    // ---- O = [P | Qf] @ Bst^T : 5 e-tiles (j=4 col 64 = den) ----
    const short* prow = &Ps[(wave * 16 + l16) * LQ];
    f32x4 acc[5];
#pragma unroll
    for (int j = 0; j < 5; j++) acc[j] = f32x4{0.f, 0.f, 0.f, 0.f};
#pragma unroll
    for (int kk = 0; kk < 4; kk++) {
        bf16x8 af = (kk < 2)
            ? *reinterpret_cast<const bf16x8*>(&prow[kk * 32 + l4 * 8])
            : *reinterpret_cast<const bf16x8*>(&arow[(kk - 2) * 32 + l4 * 8]);
#pragma unroll
        for (int j = 0; j < 5; j++) {
            bf16x8 bfv = *reinterpret_cast<const bf16x8*>(
                &Bst[(j * 16 + l16) * LB + kk * 32 + l4 * 8]);
            acc[j] = __builtin_amdgcn_mfma_f32_16x16x32_bf16(af, bfv, acc[j], 0, 0, 0);
        }
    }

    // ---- epilogue: den, mini-LN over e (in-register, shfl over l16 group) ----
#pragma unroll
    for (int r = 0; r < 4; r++) {
        float den = __shfl(acc[4][r], l4 * 16) + 1e-6f;
        float inv = 1.f / den;
        float v0 = acc[0][r] * inv, v1 = acc[1][r] * inv;
        float v2 = acc[2][r] * inv, v3 = acc[3][r] * inv;
        float s1 = v0 + v1 + v2 + v3;
        float s2 = v0 * v0 + v1 * v1 + v2 * v2 + v3 * v3;
#pragma unroll
        for (int m = 1; m < 16; m <<= 1) {
            s1 += __shfl_xor(s1, m, 64);
            s2 += __shfl_xor(s2, m, 64);
        }
        float mu = s1 * (1.f / 64.f);
        float rstd = rsqrtf(s2 * (1.f / 64.f) - mu * mu + 1e-5f);
        int l = wave * 16 + l4 * 4 + r;
        __hip_bfloat16* orow = attn + (size_t)(tok0 + l) * Dc + h * dh;
        float vj[4] = {v0, v1, v2, v3};
#pragma unroll
        for (int j = 0; j < 4; j++) {
            int e = j * 16 + l16;
            orow[e] = __float2bfloat16((vj[j] - mu) * rstd * mn_w[e] + mn_b[e]);
        }
    }
}

extern "C" void kernel_launch(void* const* d_in, const int* in_sizes, int n_in,
                              void* d_out, int out_size, void* d_ws, size_t ws_size,
                              hipStream_t stream) {
    const float* x     = (const float*)d_in[0];
    const float* Wqkv  = (const float*)d_in[1];
    const float* bqkv  = (const float*)d_in[2];
    const float* Wb1   = (const float*)d_in[3];
    const float* Wb2   = (const float*)d_in[4];
    const float* temp  = (const float*)d_in[5];
    const float* Wproj = (const float*)d_in[6];
    const float* bproj = (const float*)d_in[7];
    const float* ln_w  = (const float*)d_in[8];
    const float* ln_b  = (const float*)d_in[9];
    const float* mn_w  = (const float*)d_in[10];
    const float* mn_b  = (const float*)d_in[11];

    float* out0 = (float*)d_out;                 // [2048, 768]
    float* gate = out0 + (size_t)BL * Dc;        // [2048, 12]

    float* ws   = (float*)d_ws;
    float* tbuf = ws;                            // 2048*128 f32
    float* SU   = tbuf + (size_t)BL * Rc;        // 24*16*4096 f32 (U^T, [e][d])
    float* zc   = SU + (size_t)BH * NC * 4096;   // 24*16*64 f32
    __hip_bfloat16* bfr = (__hip_bfloat16*)(zc + (size_t)BH * NC * 64);
    __hip_bfloat16* qkvb   = bfr;                        // 2048*2304 bf16
    __hip_bfloat16* xnb    = qkvb + (size_t)BL * TD;     // 2048*768 bf16
    __hip_bfloat16* xb     = xnb + (size_t)BL * Dc;      // 2048*768 bf16 (raw x)
    __hip_bfloat16* attnb  = xb + (size_t)BL * Dc;       // 2048*768 bf16
    __hip_bfloat16* WqkvT  = attnb + (size_t)BL * Dc;    // 2304*768 bf16
    __hip_bfloat16* WprojT = WqkvT + (size_t)TD * Dc;    // 768*768 bf16
    __hip_bfloat16* Wb1T   = WprojT + (size_t)Dc * Dc;   // 128*768 bf16

    // 1. prep: weight transposes + LayerNorm
    prep_kernel<<<NPREP, 256, 0, stream>>>(x, ln_w, ln_b, Wqkv, Wproj, Wb1,
                                           xnb, xb, WqkvT, WprojT, Wb1T);
    // 2. fat dispatch: qkv GEMM (bf16 out) + bottleneck silu GEMM (fp32 out)
    fat_gemm_kernel<<<NFAT, 512, 0, stream>>>(xnb, WqkvT, bqkv, qkvb, xb, Wb1T, tbuf);
    // 3. phaseA (MFMA): per-chunk U^T + z sums + fused gate
    phaseA_kernel<<<BH * NC, 256, 0, stream>>>(qkvb, tbuf, Wb2, temp, gate, SU, zc);
    // 4. exclusive prefix over chunks
    prefix_kernel<<<(BH * 4096 + BH * 64 + 255) / 256, 256, 0, stream>>>(SU, zc);
    // 5. per-chunk outputs (MFMA) + mini-LN -> bf16
    phaseC_kernel<<<BH * NC, 256, 0, stream>>>(qkvb, gate, SU, zc, mn_w, mn_b, attnb);
    // 6. out0 = attn @ Wproj + bproj  (64x64-tile MFMA, 384 blocks)
    gemm64_kernel<<<(BL / 64) * (Dc / 64), 256, 0, stream>>>(
        attnb, WprojT, bproj, out0, BL, Dc, Dc, Dc / 64);
}